// Round 1
// baseline (380.263 us; speedup 1.0000x reference)
//
#include <hip/hip_runtime.h>

// Problem constants (from reference)
#define NB 8
#define H 512
#define W 512
#define HW (H * W)
#define C 16
#define NPIX (NB * HW)
#define SH_START 3

__device__ __forceinline__ void tap(const float* __restrict__ t, int S, int iy, int ix,
                                    float w, float acc[C]) {
    if (iy >= 0 && iy < S && ix >= 0 && ix < S) {
        const float4* p = reinterpret_cast<const float4*>(t + ((size_t)iy * S + ix) * C);
        float4 q0 = p[0];
        float4 q1 = p[1];
        float4 q2 = p[2];
        float4 q3 = p[3];
        acc[0]  = fmaf(q0.x, w, acc[0]);
        acc[1]  = fmaf(q0.y, w, acc[1]);
        acc[2]  = fmaf(q0.z, w, acc[2]);
        acc[3]  = fmaf(q0.w, w, acc[3]);
        acc[4]  = fmaf(q1.x, w, acc[4]);
        acc[5]  = fmaf(q1.y, w, acc[5]);
        acc[6]  = fmaf(q1.z, w, acc[6]);
        acc[7]  = fmaf(q1.w, w, acc[7]);
        acc[8]  = fmaf(q2.x, w, acc[8]);
        acc[9]  = fmaf(q2.y, w, acc[9]);
        acc[10] = fmaf(q2.z, w, acc[10]);
        acc[11] = fmaf(q2.w, w, acc[11]);
        acc[12] = fmaf(q3.x, w, acc[12]);
        acc[13] = fmaf(q3.y, w, acc[13]);
        acc[14] = fmaf(q3.z, w, acc[14]);
        acc[15] = fmaf(q3.w, w, acc[15]);
    }
}

__device__ __forceinline__ void sample_level(const float* __restrict__ t, int S,
                                             float u, float v, float acc[C]) {
    // Mirror the reference arithmetic exactly (fp32 op order).
    float Sf = (float)S;
    float gx = u * 2.0f - 1.0f;
    float gy = -(v * 2.0f - 1.0f);
    float ix = ((gx + 1.0f) * Sf - 1.0f) * 0.5f;
    float iy = ((gy + 1.0f) * Sf - 1.0f) * 0.5f;
    float ix0f = floorf(ix);
    float iy0f = floorf(iy);
    float wx1 = ix - ix0f;
    float wy1 = iy - iy0f;
    float wx0 = 1.0f - wx1;
    float wy0 = 1.0f - wy1;
    int ix0 = (int)ix0f;
    int iy0 = (int)iy0f;
    tap(t, S, iy0,     ix0,     wy0 * wx0, acc);
    tap(t, S, iy0,     ix0 + 1, wy0 * wx1, acc);
    tap(t, S, iy0 + 1, ix0,     wy1 * wx0, acc);
    tap(t, S, iy0 + 1, ix0 + 1, wy1 * wx1, acc);
}

__global__ __launch_bounds__(256) void texmap_kernel(
    const float* __restrict__ uv, const float* __restrict__ sh,
    const float* __restrict__ t0, const float* __restrict__ t1,
    const float* __restrict__ t2, const float* __restrict__ t3,
    float* __restrict__ out) {
    int idx = blockIdx.x * 256 + threadIdx.x;
    if (idx >= NPIX) return;

    float2 uvv = *reinterpret_cast<const float2*>(uv + (size_t)idx * 2);
    float u = uvv.x;
    float v = uvv.y;

    float acc[C];
#pragma unroll
    for (int c = 0; c < C; ++c) acc[c] = 0.0f;

    sample_level(t0, 1024, u, v, acc);
    sample_level(t1, 512,  u, v, acc);
    sample_level(t2, 256,  u, v, acc);
    sample_level(t3, 128,  u, v, acc);

    // Mask pixels where u == 0 (exact compare, as in reference)
    if (u == 0.0f) {
#pragma unroll
        for (int c = 0; c < C; ++c) acc[c] = 0.0f;
    }

    // SH multiply on channels [3, 12)
    const float* shp = sh + (size_t)idx * 9;
#pragma unroll
    for (int j = 0; j < 9; ++j) acc[SH_START + j] *= shp[j];

    // Write NCHW: out[n][c][h][w]
    int n  = idx >> 18;            // / HW (HW = 262144 = 2^18)
    int hw = idx & (HW - 1);
    float* op = out + (size_t)n * C * HW + hw;
#pragma unroll
    for (int c = 0; c < C; ++c) {
        __builtin_nontemporal_store(acc[c], op + (size_t)c * HW);
    }
}

extern "C" void kernel_launch(void* const* d_in, const int* in_sizes, int n_in,
                              void* d_out, int out_size, void* d_ws, size_t ws_size,
                              hipStream_t stream) {
    const float* uv = (const float*)d_in[0];
    const float* sh = (const float*)d_in[1];
    const float* t0 = (const float*)d_in[2];
    const float* t1 = (const float*)d_in[3];
    const float* t2 = (const float*)d_in[4];
    const float* t3 = (const float*)d_in[5];
    float* out = (float*)d_out;

    dim3 block(256);
    dim3 grid((NPIX + 255) / 256);
    texmap_kernel<<<grid, block, 0, stream>>>(uv, sh, t0, t1, t2, t3, out);
}

// Round 2
// 371.999 us; speedup vs baseline: 1.0222x; 1.0222x over previous
//
#include <hip/hip_runtime.h>

// Problem constants (from reference)
#define NB 8
#define H 512
#define W 512
#define HW (H * W)
#define C 16
#define NPIX (NB * HW)
#define SH_START 3

// Binning config
#define G 32
#define NBINS (G * G)                  // 1024
#define CNT_BLOCKS 128
#define PX_PER_CNT (NPIX / CNT_BLOCKS) // 16384
#define A_BLOCKS 8192                  // 8 blocks (reps) per bin
#define REP 8

// Workspace layout (bytes), all 16B aligned
#define OFF_RECS   ((size_t)0)                 // NPIX * 16 B  = 33554432
#define OFF_INTER  ((size_t)33554432)          // NPIX * 64 B  = 134217728
#define OFF_HIST   ((size_t)167772160)         // 128*1024*4   = 524288
#define OFF_BSTART ((size_t)168296448)         // 1025*4 -> pad 4608
#define WS_NEED    ((size_t)168301056)

__device__ __forceinline__ void tap(const float* __restrict__ t, int S, int iy, int ix,
                                    float w, float acc[C]) {
    if (iy >= 0 && iy < S && ix >= 0 && ix < S) {
        const float4* p = reinterpret_cast<const float4*>(t + ((size_t)iy * S + ix) * C);
        float4 q0 = p[0];
        float4 q1 = p[1];
        float4 q2 = p[2];
        float4 q3 = p[3];
        acc[0]  = fmaf(q0.x, w, acc[0]);
        acc[1]  = fmaf(q0.y, w, acc[1]);
        acc[2]  = fmaf(q0.z, w, acc[2]);
        acc[3]  = fmaf(q0.w, w, acc[3]);
        acc[4]  = fmaf(q1.x, w, acc[4]);
        acc[5]  = fmaf(q1.y, w, acc[5]);
        acc[6]  = fmaf(q1.z, w, acc[6]);
        acc[7]  = fmaf(q1.w, w, acc[7]);
        acc[8]  = fmaf(q2.x, w, acc[8]);
        acc[9]  = fmaf(q2.y, w, acc[9]);
        acc[10] = fmaf(q2.z, w, acc[10]);
        acc[11] = fmaf(q2.w, w, acc[11]);
        acc[12] = fmaf(q3.x, w, acc[12]);
        acc[13] = fmaf(q3.y, w, acc[13]);
        acc[14] = fmaf(q3.z, w, acc[14]);
        acc[15] = fmaf(q3.w, w, acc[15]);
    }
}

__device__ __forceinline__ void sample_level(const float* __restrict__ t, int S,
                                             float u, float v, float acc[C]) {
    float Sf = (float)S;
    float gx = u * 2.0f - 1.0f;
    float gy = -(v * 2.0f - 1.0f);
    float ix = ((gx + 1.0f) * Sf - 1.0f) * 0.5f;
    float iy = ((gy + 1.0f) * Sf - 1.0f) * 0.5f;
    float ix0f = floorf(ix);
    float iy0f = floorf(iy);
    float wx1 = ix - ix0f;
    float wy1 = iy - iy0f;
    float wx0 = 1.0f - wx1;
    float wy0 = 1.0f - wy1;
    int ix0 = (int)ix0f;
    int iy0 = (int)iy0f;
    tap(t, S, iy0,     ix0,     wy0 * wx0, acc);
    tap(t, S, iy0,     ix0 + 1, wy0 * wx1, acc);
    tap(t, S, iy0 + 1, ix0,     wy1 * wx0, acc);
    tap(t, S, iy0 + 1, ix0 + 1, wy1 * wx1, acc);
}

__device__ __forceinline__ int bin_of(float u, float v) {
    int bx = (int)(u * (float)G);
    int by = (int)(v * (float)G);
    bx = bx < 0 ? 0 : (bx > G - 1 ? G - 1 : bx);
    by = by < 0 ? 0 : (by > G - 1 ? G - 1 : by);
    return by * G + bx;
}

// ---------------- K1: per-block histogram ----------------
__global__ __launch_bounds__(256) void count_kernel(const float* __restrict__ uv,
                                                    int* __restrict__ hist) {
    __shared__ int h[NBINS];
    for (int i = threadIdx.x; i < NBINS; i += 256) h[i] = 0;
    __syncthreads();
    int base = blockIdx.x * PX_PER_CNT;
    const float2* uv2 = reinterpret_cast<const float2*>(uv);
    for (int i = threadIdx.x; i < PX_PER_CNT; i += 256) {
        float2 p = uv2[base + i];
        atomicAdd(&h[bin_of(p.x, p.y)], 1);
    }
    __syncthreads();
    for (int i = threadIdx.x; i < NBINS; i += 256)
        hist[blockIdx.x * NBINS + i] = h[i];
}

// ---------------- K2: scan (per-bin over blocks, then over bins) ----------------
__global__ __launch_bounds__(1024) void scan_kernel(int* __restrict__ hist,
                                                    int* __restrict__ bin_start) {
    __shared__ int sm[NBINS];
    int b = threadIdx.x;
    int run = 0;
    for (int blk = 0; blk < CNT_BLOCKS; ++blk) {
        int t = hist[blk * NBINS + b];
        hist[blk * NBINS + b] = run;  // per-block base within bin
        run += t;
    }
    int total = run;
    sm[b] = total;
    __syncthreads();
    // inclusive scan over bins (Hillis-Steele)
    for (int off = 1; off < NBINS; off <<= 1) {
        int v = (b >= off) ? sm[b - off] : 0;
        __syncthreads();
        sm[b] += v;
        __syncthreads();
    }
    int incl = sm[b];
    bin_start[b] = incl - total;  // exclusive
    if (b == NBINS - 1) bin_start[NBINS] = incl;
}

// ---------------- K3: scatter pixels into binned records ----------------
__global__ __launch_bounds__(256) void scatter_kernel(const float* __restrict__ uv,
                                                      const int* __restrict__ hist,
                                                      const int* __restrict__ bin_start,
                                                      float4* __restrict__ recs) {
    __shared__ int cur[NBINS];
    for (int i = threadIdx.x; i < NBINS; i += 256)
        cur[i] = bin_start[i] + hist[blockIdx.x * NBINS + i];
    __syncthreads();
    int base = blockIdx.x * PX_PER_CNT;
    const float2* uv2 = reinterpret_cast<const float2*>(uv);
    for (int i = threadIdx.x; i < PX_PER_CNT; i += 256) {
        int pix = base + i;
        float2 p = uv2[pix];
        int bin = bin_of(p.x, p.y);
        int pos = atomicAdd(&cur[bin], 1);
        recs[pos] = make_float4(p.x, p.y, __int_as_float(pix), 0.0f);
    }
}

// ---------------- K4: binned sampling -> intermediate [pix][16] ----------------
__global__ __launch_bounds__(256) void phaseA_kernel(
    const float4* __restrict__ recs, const int* __restrict__ bin_start,
    const float* __restrict__ t0, const float* __restrict__ t1,
    const float* __restrict__ t2, const float* __restrict__ t3,
    float* __restrict__ inter) {
    int blk = blockIdx.x;
    int xcd = blk & 7;
    int slot = blk >> 3;          // 0..1023
    int bin_local = slot >> 3;    // 0..127
    int rep = slot & 7;           // 0..7
    int bin = xcd * (NBINS / 8) + bin_local;
    int start = bin_start[bin];
    int cnt = bin_start[bin + 1] - start;

    for (int i = rep * 256 + threadIdx.x; i < cnt; i += REP * 256) {
        float4 r = recs[start + i];
        float u = r.x, v = r.y;
        int pix = __float_as_int(r.z);

        float acc[C];
#pragma unroll
        for (int c = 0; c < C; ++c) acc[c] = 0.0f;

        sample_level(t0, 1024, u, v, acc);
        sample_level(t1, 512,  u, v, acc);
        sample_level(t2, 256,  u, v, acc);
        sample_level(t3, 128,  u, v, acc);

        if (u == 0.0f) {
#pragma unroll
            for (int c = 0; c < C; ++c) acc[c] = 0.0f;
        }

        float4* op = reinterpret_cast<float4*>(inter + (size_t)pix * C);
        op[0] = make_float4(acc[0],  acc[1],  acc[2],  acc[3]);
        op[1] = make_float4(acc[4],  acc[5],  acc[6],  acc[7]);
        op[2] = make_float4(acc[8],  acc[9],  acc[10], acc[11]);
        op[3] = make_float4(acc[12], acc[13], acc[14], acc[15]);
    }
}

// ---------------- K5: pixel-ordered SH multiply + NCHW transpose write ----------------
__global__ __launch_bounds__(256) void phaseB_kernel(const float* __restrict__ inter,
                                                     const float* __restrict__ sh,
                                                     float* __restrict__ out) {
    __shared__ float shs[256 * 9];
    int base = blockIdx.x * 256;
    const float* shp = sh + (size_t)base * 9;
    for (int i = threadIdx.x; i < 256 * 9; i += 256) shs[i] = shp[i];
    __syncthreads();

    int pix = base + threadIdx.x;
    const float4* ip = reinterpret_cast<const float4*>(inter + (size_t)pix * C);
    float4 a0 = ip[0];
    float4 a1 = ip[1];
    float4 a2 = ip[2];
    float4 a3 = ip[3];
    const float* s = &shs[threadIdx.x * 9];

    a0.w *= s[0];
    a1.x *= s[1]; a1.y *= s[2]; a1.z *= s[3]; a1.w *= s[4];
    a2.x *= s[5]; a2.y *= s[6]; a2.z *= s[7]; a2.w *= s[8];

    int n  = pix >> 18;
    int hw = pix & (HW - 1);
    float* op = out + (size_t)n * C * HW + hw;
    __builtin_nontemporal_store(a0.x, op + 0 * HW);
    __builtin_nontemporal_store(a0.y, op + 1 * HW);
    __builtin_nontemporal_store(a0.z, op + 2 * HW);
    __builtin_nontemporal_store(a0.w, op + 3 * HW);
    __builtin_nontemporal_store(a1.x, op + 4 * HW);
    __builtin_nontemporal_store(a1.y, op + 5 * HW);
    __builtin_nontemporal_store(a1.z, op + 6 * HW);
    __builtin_nontemporal_store(a1.w, op + 7 * HW);
    __builtin_nontemporal_store(a2.x, op + (size_t)8 * HW);
    __builtin_nontemporal_store(a2.y, op + (size_t)9 * HW);
    __builtin_nontemporal_store(a2.z, op + (size_t)10 * HW);
    __builtin_nontemporal_store(a2.w, op + (size_t)11 * HW);
    __builtin_nontemporal_store(a3.x, op + (size_t)12 * HW);
    __builtin_nontemporal_store(a3.y, op + (size_t)13 * HW);
    __builtin_nontemporal_store(a3.z, op + (size_t)14 * HW);
    __builtin_nontemporal_store(a3.w, op + (size_t)15 * HW);
}

// ---------------- Fallback: round-1 monolithic kernel ----------------
__global__ __launch_bounds__(256) void texmap_kernel(
    const float* __restrict__ uv, const float* __restrict__ sh,
    const float* __restrict__ t0, const float* __restrict__ t1,
    const float* __restrict__ t2, const float* __restrict__ t3,
    float* __restrict__ out) {
    int idx = blockIdx.x * 256 + threadIdx.x;
    if (idx >= NPIX) return;

    float2 uvv = *reinterpret_cast<const float2*>(uv + (size_t)idx * 2);
    float u = uvv.x;
    float v = uvv.y;

    float acc[C];
#pragma unroll
    for (int c = 0; c < C; ++c) acc[c] = 0.0f;

    sample_level(t0, 1024, u, v, acc);
    sample_level(t1, 512,  u, v, acc);
    sample_level(t2, 256,  u, v, acc);
    sample_level(t3, 128,  u, v, acc);

    if (u == 0.0f) {
#pragma unroll
        for (int c = 0; c < C; ++c) acc[c] = 0.0f;
    }

    const float* shp = sh + (size_t)idx * 9;
#pragma unroll
    for (int j = 0; j < 9; ++j) acc[SH_START + j] *= shp[j];

    int n  = idx >> 18;
    int hw = idx & (HW - 1);
    float* op = out + (size_t)n * C * HW + hw;
#pragma unroll
    for (int c = 0; c < C; ++c) {
        __builtin_nontemporal_store(acc[c], op + (size_t)c * HW);
    }
}

extern "C" void kernel_launch(void* const* d_in, const int* in_sizes, int n_in,
                              void* d_out, int out_size, void* d_ws, size_t ws_size,
                              hipStream_t stream) {
    const float* uv = (const float*)d_in[0];
    const float* sh = (const float*)d_in[1];
    const float* t0 = (const float*)d_in[2];
    const float* t1 = (const float*)d_in[3];
    const float* t2 = (const float*)d_in[4];
    const float* t3 = (const float*)d_in[5];
    float* out = (float*)d_out;

    if (ws_size < WS_NEED) {
        // Not enough scratch: monolithic fallback (round-1 kernel, known-correct)
        texmap_kernel<<<dim3((NPIX + 255) / 256), dim3(256), 0, stream>>>(
            uv, sh, t0, t1, t2, t3, out);
        return;
    }

    char* ws = (char*)d_ws;
    float4* recs    = (float4*)(ws + OFF_RECS);
    float*  inter   = (float*)(ws + OFF_INTER);
    int*    hist    = (int*)(ws + OFF_HIST);
    int*    bstart  = (int*)(ws + OFF_BSTART);

    count_kernel<<<dim3(CNT_BLOCKS), dim3(256), 0, stream>>>(uv, hist);
    scan_kernel<<<dim3(1), dim3(1024), 0, stream>>>(hist, bstart);
    scatter_kernel<<<dim3(CNT_BLOCKS), dim3(256), 0, stream>>>(uv, hist, bstart, recs);
    phaseA_kernel<<<dim3(A_BLOCKS), dim3(256), 0, stream>>>(
        recs, bstart, t0, t1, t2, t3, inter);
    phaseB_kernel<<<dim3(NPIX / 256), dim3(256), 0, stream>>>(inter, sh, out);
}

// Round 3
// 307.064 us; speedup vs baseline: 1.2384x; 1.2115x over previous
//
#include <hip/hip_runtime.h>

// Problem constants (from reference)
#define NB 8
#define H 512
#define W 512
#define HW (H * W)
#define C 16
#define NPIX (NB * HW)
#define SH_START 3

// Binning config
#define G 32
#define NBINS (G * G)                  // 1024
#define CNT_BLOCKS 128
#define PX_PER_CNT (NPIX / CNT_BLOCKS) // 16384
#define A_BLOCKS 8192                  // 8 blocks (reps) per bin
#define REP 8

// Workspace layout (bytes), all 16B aligned
#define OFF_RECS   ((size_t)0)                 // NPIX * 16 B  = 33554432
#define OFF_INTER  ((size_t)33554432)          // NPIX * 64 B  = 134217728
#define OFF_HIST   ((size_t)167772160)         // 1024*128*4   = 524288 (transposed: [bin][blk])
#define OFF_BSTART ((size_t)168296448)         // 1025*4 -> pad 4608
#define WS_NEED    ((size_t)168301056)

typedef float f32x4 __attribute__((ext_vector_type(4)));

__device__ __forceinline__ int bin_of(float u, float v) {
    int bx = (int)(u * (float)G);
    int by = (int)(v * (float)G);
    bx = bx < 0 ? 0 : (bx > G - 1 ? G - 1 : bx);
    by = by < 0 ? 0 : (by > G - 1 ? G - 1 : by);
    return by * G + bx;
}

// ---------------- K1: per-block histogram (transposed output [bin][blk]) ----------------
__global__ __launch_bounds__(256) void count_kernel(const float* __restrict__ uv,
                                                    int* __restrict__ hist) {
    __shared__ int h[NBINS];
    for (int i = threadIdx.x; i < NBINS; i += 256) h[i] = 0;
    __syncthreads();
    int base = blockIdx.x * PX_PER_CNT;
    const float2* uv2 = reinterpret_cast<const float2*>(uv);
    for (int i = threadIdx.x; i < PX_PER_CNT; i += 256) {
        float2 p = uv2[base + i];
        atomicAdd(&h[bin_of(p.x, p.y)], 1);
    }
    __syncthreads();
    for (int i = threadIdx.x; i < NBINS; i += 256)
        hist[i * CNT_BLOCKS + blockIdx.x] = h[i];
}

// ---------------- K2: scan (serial over blocks per bin w/ int4, then over bins) --------
__global__ __launch_bounds__(1024) void scan_kernel(int* __restrict__ hist,
                                                    int* __restrict__ bin_start) {
    __shared__ int sm[NBINS];
    int b = threadIdx.x;
    int4* row4 = reinterpret_cast<int4*>(hist + b * CNT_BLOCKS);
    int run = 0;
#pragma unroll
    for (int k = 0; k < CNT_BLOCKS / 4; ++k) {
        int4 t = row4[k];
        int4 o;
        o.x = run; run += t.x;
        o.y = run; run += t.y;
        o.z = run; run += t.z;
        o.w = run; run += t.w;
        row4[k] = o;  // per-block base within bin
    }
    int total = run;
    sm[b] = total;
    __syncthreads();
    // inclusive scan over bins (Hillis-Steele)
    for (int off = 1; off < NBINS; off <<= 1) {
        int v = (b >= off) ? sm[b - off] : 0;
        __syncthreads();
        sm[b] += v;
        __syncthreads();
    }
    int incl = sm[b];
    bin_start[b] = incl - total;  // exclusive
    if (b == NBINS - 1) bin_start[NBINS] = incl;
}

// ---------------- K3: scatter pixels into binned records ----------------
__global__ __launch_bounds__(256) void scatter_kernel(const float* __restrict__ uv,
                                                      const int* __restrict__ hist,
                                                      const int* __restrict__ bin_start,
                                                      float4* __restrict__ recs) {
    __shared__ int cur[NBINS];
    for (int i = threadIdx.x; i < NBINS; i += 256)
        cur[i] = bin_start[i] + hist[i * CNT_BLOCKS + blockIdx.x];
    __syncthreads();
    int base = blockIdx.x * PX_PER_CNT;
    const float2* uv2 = reinterpret_cast<const float2*>(uv);
    for (int i = threadIdx.x; i < PX_PER_CNT; i += 256) {
        int pix = base + i;
        float2 p = uv2[pix];
        int bin = bin_of(p.x, p.y);
        int pos = atomicAdd(&cur[bin], 1);
        recs[pos] = make_float4(p.x, p.y, __int_as_float(pix), 0.0f);
    }
}

// ---------------- K4: binned sampling, quad-lane: 4 lanes per pixel ----------------
// lane = 4*q + ch : quad q handles record (i+q); ch selects 16B chunk of each 64B texel.
__device__ __forceinline__ void tapq(const float* __restrict__ t, int S, int iy, int ix,
                                     float w, int ch, f32x4& acc) {
    if (iy >= 0 && iy < S && ix >= 0 && ix < S) {
        const f32x4* p = reinterpret_cast<const f32x4*>(t + ((size_t)(iy * S + ix)) * C) + ch;
        f32x4 q = *p;
        acc.x = fmaf(q.x, w, acc.x);
        acc.y = fmaf(q.y, w, acc.y);
        acc.z = fmaf(q.z, w, acc.z);
        acc.w = fmaf(q.w, w, acc.w);
    }
}

__device__ __forceinline__ void sample_level_q(const float* __restrict__ t, int S,
                                               float u, float v, int ch, f32x4& acc) {
    float Sf = (float)S;
    float gx = u * 2.0f - 1.0f;
    float gy = -(v * 2.0f - 1.0f);
    float ix = ((gx + 1.0f) * Sf - 1.0f) * 0.5f;
    float iy = ((gy + 1.0f) * Sf - 1.0f) * 0.5f;
    float ix0f = floorf(ix);
    float iy0f = floorf(iy);
    float wx1 = ix - ix0f;
    float wy1 = iy - iy0f;
    float wx0 = 1.0f - wx1;
    float wy0 = 1.0f - wy1;
    int ix0 = (int)ix0f;
    int iy0 = (int)iy0f;
    tapq(t, S, iy0,     ix0,     wy0 * wx0, ch, acc);
    tapq(t, S, iy0,     ix0 + 1, wy0 * wx1, ch, acc);
    tapq(t, S, iy0 + 1, ix0,     wy1 * wx0, ch, acc);
    tapq(t, S, iy0 + 1, ix0 + 1, wy1 * wx1, ch, acc);
}

__global__ __launch_bounds__(256) void phaseA_kernel(
    const float4* __restrict__ recs, const int* __restrict__ bin_start,
    const float* __restrict__ t0, const float* __restrict__ t1,
    const float* __restrict__ t2, const float* __restrict__ t3,
    float* __restrict__ inter) {
    int blk = blockIdx.x;
    int xcd = blk & 7;
    int slot = blk >> 3;          // 0..1023
    int bin_local = slot >> 3;    // 0..127
    int rep = slot & 7;           // 0..7
    int bin = xcd * (NBINS / 8) + bin_local;
    int start = bin_start[bin];
    int cnt = bin_start[bin + 1] - start;

    int wave = threadIdx.x >> 6;  // 0..3
    int lane = threadIdx.x & 63;
    int q  = lane >> 2;           // 0..15: record within batch
    int ch = lane & 3;            // 0..3 : 16B chunk of texel

    int wslot = rep * 4 + wave;   // 0..31 (32 waves per bin)
    for (int i = wslot * 16; i < cnt; i += 32 * 16) {
        int ridx = i + q;
        if (ridx >= cnt) continue;
        float4 r = recs[start + ridx];
        float u = r.x, v = r.y;
        int pix = __float_as_int(r.z);

        f32x4 acc = {0.0f, 0.0f, 0.0f, 0.0f};
        sample_level_q(t0, 1024, u, v, ch, acc);
        sample_level_q(t1, 512,  u, v, ch, acc);
        sample_level_q(t2, 256,  u, v, ch, acc);
        sample_level_q(t3, 128,  u, v, ch, acc);

        if (u == 0.0f) {
            acc = (f32x4){0.0f, 0.0f, 0.0f, 0.0f};
        }

        f32x4* op = reinterpret_cast<f32x4*>(inter + (size_t)pix * C) + ch;
        __builtin_nontemporal_store(acc, op);
    }
}

// ---------------- K5: pixel-ordered SH multiply + NCHW transpose write ----------------
__global__ __launch_bounds__(256) void phaseB_kernel(const float* __restrict__ inter,
                                                     const float* __restrict__ sh,
                                                     float* __restrict__ out) {
    __shared__ float shs[256 * 9];
    int base = blockIdx.x * 256;
    const float* shp = sh + (size_t)base * 9;
    for (int i = threadIdx.x; i < 256 * 9; i += 256) shs[i] = shp[i];
    __syncthreads();

    int pix = base + threadIdx.x;
    const float4* ip = reinterpret_cast<const float4*>(inter + (size_t)pix * C);
    float4 a0 = ip[0];
    float4 a1 = ip[1];
    float4 a2 = ip[2];
    float4 a3 = ip[3];
    const float* s = &shs[threadIdx.x * 9];

    a0.w *= s[0];
    a1.x *= s[1]; a1.y *= s[2]; a1.z *= s[3]; a1.w *= s[4];
    a2.x *= s[5]; a2.y *= s[6]; a2.z *= s[7]; a2.w *= s[8];

    int n  = pix >> 18;
    int hw = pix & (HW - 1);
    float* op = out + (size_t)n * C * HW + hw;
    __builtin_nontemporal_store(a0.x, op + 0 * HW);
    __builtin_nontemporal_store(a0.y, op + 1 * HW);
    __builtin_nontemporal_store(a0.z, op + 2 * HW);
    __builtin_nontemporal_store(a0.w, op + 3 * HW);
    __builtin_nontemporal_store(a1.x, op + 4 * HW);
    __builtin_nontemporal_store(a1.y, op + 5 * HW);
    __builtin_nontemporal_store(a1.z, op + 6 * HW);
    __builtin_nontemporal_store(a1.w, op + 7 * HW);
    __builtin_nontemporal_store(a2.x, op + (size_t)8 * HW);
    __builtin_nontemporal_store(a2.y, op + (size_t)9 * HW);
    __builtin_nontemporal_store(a2.z, op + (size_t)10 * HW);
    __builtin_nontemporal_store(a2.w, op + (size_t)11 * HW);
    __builtin_nontemporal_store(a3.x, op + (size_t)12 * HW);
    __builtin_nontemporal_store(a3.y, op + (size_t)13 * HW);
    __builtin_nontemporal_store(a3.z, op + (size_t)14 * HW);
    __builtin_nontemporal_store(a3.w, op + (size_t)15 * HW);
}

// ---------------- Fallback: round-1 monolithic kernel ----------------
__device__ __forceinline__ void tap(const float* __restrict__ t, int S, int iy, int ix,
                                    float w, float acc[C]) {
    if (iy >= 0 && iy < S && ix >= 0 && ix < S) {
        const float4* p = reinterpret_cast<const float4*>(t + ((size_t)iy * S + ix) * C);
        float4 q0 = p[0];
        float4 q1 = p[1];
        float4 q2 = p[2];
        float4 q3 = p[3];
        acc[0]  = fmaf(q0.x, w, acc[0]);
        acc[1]  = fmaf(q0.y, w, acc[1]);
        acc[2]  = fmaf(q0.z, w, acc[2]);
        acc[3]  = fmaf(q0.w, w, acc[3]);
        acc[4]  = fmaf(q1.x, w, acc[4]);
        acc[5]  = fmaf(q1.y, w, acc[5]);
        acc[6]  = fmaf(q1.z, w, acc[6]);
        acc[7]  = fmaf(q1.w, w, acc[7]);
        acc[8]  = fmaf(q2.x, w, acc[8]);
        acc[9]  = fmaf(q2.y, w, acc[9]);
        acc[10] = fmaf(q2.z, w, acc[10]);
        acc[11] = fmaf(q2.w, w, acc[11]);
        acc[12] = fmaf(q3.x, w, acc[12]);
        acc[13] = fmaf(q3.y, w, acc[13]);
        acc[14] = fmaf(q3.z, w, acc[14]);
        acc[15] = fmaf(q3.w, w, acc[15]);
    }
}

__device__ __forceinline__ void sample_level(const float* __restrict__ t, int S,
                                             float u, float v, float acc[C]) {
    float Sf = (float)S;
    float gx = u * 2.0f - 1.0f;
    float gy = -(v * 2.0f - 1.0f);
    float ix = ((gx + 1.0f) * Sf - 1.0f) * 0.5f;
    float iy = ((gy + 1.0f) * Sf - 1.0f) * 0.5f;
    float ix0f = floorf(ix);
    float iy0f = floorf(iy);
    float wx1 = ix - ix0f;
    float wy1 = iy - iy0f;
    float wx0 = 1.0f - wx1;
    float wy0 = 1.0f - wy1;
    int ix0 = (int)ix0f;
    int iy0 = (int)iy0f;
    tap(t, S, iy0,     ix0,     wy0 * wx0, acc);
    tap(t, S, iy0,     ix0 + 1, wy0 * wx1, acc);
    tap(t, S, iy0 + 1, ix0,     wy1 * wx0, acc);
    tap(t, S, iy0 + 1, ix0 + 1, wy1 * wx1, acc);
}

__global__ __launch_bounds__(256) void texmap_kernel(
    const float* __restrict__ uv, const float* __restrict__ sh,
    const float* __restrict__ t0, const float* __restrict__ t1,
    const float* __restrict__ t2, const float* __restrict__ t3,
    float* __restrict__ out) {
    int idx = blockIdx.x * 256 + threadIdx.x;
    if (idx >= NPIX) return;

    float2 uvv = *reinterpret_cast<const float2*>(uv + (size_t)idx * 2);
    float u = uvv.x;
    float v = uvv.y;

    float acc[C];
#pragma unroll
    for (int c = 0; c < C; ++c) acc[c] = 0.0f;

    sample_level(t0, 1024, u, v, acc);
    sample_level(t1, 512,  u, v, acc);
    sample_level(t2, 256,  u, v, acc);
    sample_level(t3, 128,  u, v, acc);

    if (u == 0.0f) {
#pragma unroll
        for (int c = 0; c < C; ++c) acc[c] = 0.0f;
    }

    const float* shp = sh + (size_t)idx * 9;
#pragma unroll
    for (int j = 0; j < 9; ++j) acc[SH_START + j] *= shp[j];

    int n  = idx >> 18;
    int hw = idx & (HW - 1);
    float* op = out + (size_t)n * C * HW + hw;
#pragma unroll
    for (int c = 0; c < C; ++c) {
        __builtin_nontemporal_store(acc[c], op + (size_t)c * HW);
    }
}

extern "C" void kernel_launch(void* const* d_in, const int* in_sizes, int n_in,
                              void* d_out, int out_size, void* d_ws, size_t ws_size,
                              hipStream_t stream) {
    const float* uv = (const float*)d_in[0];
    const float* sh = (const float*)d_in[1];
    const float* t0 = (const float*)d_in[2];
    const float* t1 = (const float*)d_in[3];
    const float* t2 = (const float*)d_in[4];
    const float* t3 = (const float*)d_in[5];
    float* out = (float*)d_out;

    if (ws_size < WS_NEED) {
        texmap_kernel<<<dim3((NPIX + 255) / 256), dim3(256), 0, stream>>>(
            uv, sh, t0, t1, t2, t3, out);
        return;
    }

    char* ws = (char*)d_ws;
    float4* recs    = (float4*)(ws + OFF_RECS);
    float*  inter   = (float*)(ws + OFF_INTER);
    int*    hist    = (int*)(ws + OFF_HIST);
    int*    bstart  = (int*)(ws + OFF_BSTART);

    count_kernel<<<dim3(CNT_BLOCKS), dim3(256), 0, stream>>>(uv, hist);
    scan_kernel<<<dim3(1), dim3(1024), 0, stream>>>(hist, bstart);
    scatter_kernel<<<dim3(CNT_BLOCKS), dim3(256), 0, stream>>>(uv, hist, bstart, recs);
    phaseA_kernel<<<dim3(A_BLOCKS), dim3(256), 0, stream>>>(
        recs, bstart, t0, t1, t2, t3, inter);
    phaseB_kernel<<<dim3(NPIX / 256), dim3(256), 0, stream>>>(inter, sh, out);
}

// Round 4
// 227.524 us; speedup vs baseline: 1.6713x; 1.3496x over previous
//
#include <hip/hip_runtime.h>

// Problem constants (from reference)
#define NB 8
#define H 512
#define W 512
#define HW (H * W)
#define C 16
#define NPIX (NB * HW)
#define SH_START 3

// Binning config
#define G 32
#define NBINS (G * G)                  // 1024
#define CNT_BLOCKS 128
#define PX_PER_CNT (NPIX / CNT_BLOCKS) // 16384

// Workspace layout (bytes), all 16B aligned
#define OFF_RECS   ((size_t)0)                 // NPIX * 16 B  = 33554432
#define OFF_INTER  ((size_t)33554432)          // NPIX * 64 B  = 134217728
#define OFF_HIST   ((size_t)167772160)         // 1024*128*4   = 524288 (transposed: [bin][blk])
#define OFF_BSTART ((size_t)168296448)         // 1025*4 -> pad 4608
#define WS_NEED    ((size_t)168301056)

// LDS float-offsets for the 4 staged mip regions (texel stride = 16 floats = 64B)
#define LDS0 0        // 34*34 texels
#define LDS1 18496    // 18*18
#define LDS2 23680    // 10*10
#define LDS3 25280    // 6*6
#define LDS_FLOATS 25856  // 103,424 bytes

typedef float f32x4 __attribute__((ext_vector_type(4)));

__device__ __forceinline__ int bin_of(float u, float v) {
    int bx = (int)(u * (float)G);
    int by = (int)(v * (float)G);
    bx = bx < 0 ? 0 : (bx > G - 1 ? G - 1 : bx);
    by = by < 0 ? 0 : (by > G - 1 ? G - 1 : by);
    return by * G + bx;
}

// ---------------- K1: per-block histogram (transposed output [bin][blk]) ----------------
__global__ __launch_bounds__(256) void count_kernel(const float* __restrict__ uv,
                                                    int* __restrict__ hist) {
    __shared__ int h[NBINS];
    for (int i = threadIdx.x; i < NBINS; i += 256) h[i] = 0;
    __syncthreads();
    int base = blockIdx.x * PX_PER_CNT;
    const float2* uv2 = reinterpret_cast<const float2*>(uv);
    for (int i = threadIdx.x; i < PX_PER_CNT; i += 256) {
        float2 p = uv2[base + i];
        atomicAdd(&h[bin_of(p.x, p.y)], 1);
    }
    __syncthreads();
    for (int i = threadIdx.x; i < NBINS; i += 256)
        hist[i * CNT_BLOCKS + blockIdx.x] = h[i];
}

// ---------------- K2: scan (serial over blocks per bin w/ int4, then over bins) --------
__global__ __launch_bounds__(1024) void scan_kernel(int* __restrict__ hist,
                                                    int* __restrict__ bin_start) {
    __shared__ int sm[NBINS];
    int b = threadIdx.x;
    int4* row4 = reinterpret_cast<int4*>(hist + b * CNT_BLOCKS);
    int run = 0;
#pragma unroll
    for (int k = 0; k < CNT_BLOCKS / 4; ++k) {
        int4 t = row4[k];
        int4 o;
        o.x = run; run += t.x;
        o.y = run; run += t.y;
        o.z = run; run += t.z;
        o.w = run; run += t.w;
        row4[k] = o;  // per-block base within bin
    }
    int total = run;
    sm[b] = total;
    __syncthreads();
    for (int off = 1; off < NBINS; off <<= 1) {
        int v = (b >= off) ? sm[b - off] : 0;
        __syncthreads();
        sm[b] += v;
        __syncthreads();
    }
    int incl = sm[b];
    bin_start[b] = incl - total;  // exclusive
    if (b == NBINS - 1) bin_start[NBINS] = incl;
}

// ---------------- K3: scatter pixels into binned records ----------------
__global__ __launch_bounds__(256) void scatter_kernel(const float* __restrict__ uv,
                                                      const int* __restrict__ hist,
                                                      const int* __restrict__ bin_start,
                                                      float4* __restrict__ recs) {
    __shared__ int cur[NBINS];
    for (int i = threadIdx.x; i < NBINS; i += 256)
        cur[i] = bin_start[i] + hist[i * CNT_BLOCKS + blockIdx.x];
    __syncthreads();
    int base = blockIdx.x * PX_PER_CNT;
    const float2* uv2 = reinterpret_cast<const float2*>(uv);
    for (int i = threadIdx.x; i < PX_PER_CNT; i += 256) {
        int pix = base + i;
        float2 p = uv2[pix];
        int bin = bin_of(p.x, p.y);
        int pos = atomicAdd(&cur[bin], 1);
        recs[pos] = make_float4(p.x, p.y, __int_as_float(pix), 0.0f);
    }
}

// ---------------- K4: LDS-staged binned sampling ----------------
template<int S, int N>
__device__ __forceinline__ void stage_mip(const float* __restrict__ t,
                                          float* __restrict__ lbase,
                                          int x0, int y0, int tid) {
    // N*N texels, 4 chunks of 16B each; OOB texels stored as zeros.
    for (int i = tid; i < N * N * 4; i += 1024) {
        int tx = i >> 2, ch = i & 3;
        int ly = tx / N, lx = tx - ly * N;
        int gy = y0 + ly, gx = x0 + lx;
        f32x4 val = {0.0f, 0.0f, 0.0f, 0.0f};
        if (gy >= 0 && gy < S && gx >= 0 && gx < S)
            val = *reinterpret_cast<const f32x4*>(t + ((size_t)(gy * S + gx)) * C + ch * 4);
        *reinterpret_cast<f32x4*>(lbase + (ly * N + lx) * 16 + ch * 4) = val;
    }
}

template<int S, int N>
__device__ __forceinline__ void sample_mip_lds(const float* __restrict__ lbase,
                                               int x0, int y0,
                                               float u, float v, int ch4, f32x4& acc) {
    // Mirror reference arithmetic exactly (fp32 op order).
    float Sf = (float)S;
    float gx = u * 2.0f - 1.0f;
    float gy = -(v * 2.0f - 1.0f);
    float ix = ((gx + 1.0f) * Sf - 1.0f) * 0.5f;
    float iy = ((gy + 1.0f) * Sf - 1.0f) * 0.5f;
    float ix0f = floorf(ix);
    float iy0f = floorf(iy);
    float wx1 = ix - ix0f;
    float wy1 = iy - iy0f;
    float wx0 = 1.0f - wx1;
    float wy0 = 1.0f - wy1;
    int lx = (int)ix0f - x0;
    int ly = (int)iy0f - y0;
    const float* p = lbase + (ly * N + lx) * 16 + ch4;
    f32x4 t00 = *reinterpret_cast<const f32x4*>(p);
    f32x4 t01 = *reinterpret_cast<const f32x4*>(p + 16);
    f32x4 t10 = *reinterpret_cast<const f32x4*>(p + 16 * N);
    f32x4 t11 = *reinterpret_cast<const f32x4*>(p + 16 * N + 16);
    float w00 = wy0 * wx0, w01 = wy0 * wx1, w10 = wy1 * wx0, w11 = wy1 * wx1;
    acc.x = fmaf(t00.x, w00, acc.x);
    acc.y = fmaf(t00.y, w00, acc.y);
    acc.z = fmaf(t00.z, w00, acc.z);
    acc.w = fmaf(t00.w, w00, acc.w);
    acc.x = fmaf(t01.x, w01, acc.x);
    acc.y = fmaf(t01.y, w01, acc.y);
    acc.z = fmaf(t01.z, w01, acc.z);
    acc.w = fmaf(t01.w, w01, acc.w);
    acc.x = fmaf(t10.x, w10, acc.x);
    acc.y = fmaf(t10.y, w10, acc.y);
    acc.z = fmaf(t10.z, w10, acc.z);
    acc.w = fmaf(t10.w, w10, acc.w);
    acc.x = fmaf(t11.x, w11, acc.x);
    acc.y = fmaf(t11.y, w11, acc.y);
    acc.z = fmaf(t11.z, w11, acc.z);
    acc.w = fmaf(t11.w, w11, acc.w);
}

__global__ __launch_bounds__(1024) void phaseA_kernel(
    const float4* __restrict__ recs, const int* __restrict__ bin_start,
    const float* __restrict__ t0, const float* __restrict__ t1,
    const float* __restrict__ t2, const float* __restrict__ t3,
    float* __restrict__ inter) {
    __shared__ float lds[LDS_FLOATS];
    int bin = blockIdx.x;
    int bx = bin & (G - 1), by = bin >> 5;
    int tid = threadIdx.x;

    const int x0_0 = bx * 32 - 1, y0_0 = 1024 - (by + 1) * 32 - 1;
    const int x0_1 = bx * 16 - 1, y0_1 = 512  - (by + 1) * 16 - 1;
    const int x0_2 = bx * 8  - 1, y0_2 = 256  - (by + 1) * 8  - 1;
    const int x0_3 = bx * 4  - 1, y0_3 = 128  - (by + 1) * 4  - 1;

    stage_mip<1024, 34>(t0, lds + LDS0, x0_0, y0_0, tid);
    stage_mip<512,  18>(t1, lds + LDS1, x0_1, y0_1, tid);
    stage_mip<256,  10>(t2, lds + LDS2, x0_2, y0_2, tid);
    stage_mip<128,   6>(t3, lds + LDS3, x0_3, y0_3, tid);
    __syncthreads();

    int start = bin_start[bin];
    int cnt = bin_start[bin + 1] - start;

    int wave = tid >> 6;
    int lane = tid & 63;
    int q    = lane >> 2;       // 0..15 record within batch
    int chq  = lane & 3;        // 0..3  16B chunk
    int ch4  = chq * 4;

    for (int i0 = wave * 16; i0 < cnt; i0 += 16 * 16) {
        int i = i0 + q;
        if (i < cnt) {
            float4 r = recs[start + i];
            float u = r.x, v = r.y;
            int pix = __float_as_int(r.z);

            f32x4 acc = {0.0f, 0.0f, 0.0f, 0.0f};
            sample_mip_lds<1024, 34>(lds + LDS0, x0_0, y0_0, u, v, ch4, acc);
            sample_mip_lds<512,  18>(lds + LDS1, x0_1, y0_1, u, v, ch4, acc);
            sample_mip_lds<256,  10>(lds + LDS2, x0_2, y0_2, u, v, ch4, acc);
            sample_mip_lds<128,   6>(lds + LDS3, x0_3, y0_3, u, v, ch4, acc);

            if (u == 0.0f) acc = (f32x4){0.0f, 0.0f, 0.0f, 0.0f};

            f32x4* op = reinterpret_cast<f32x4*>(inter + (size_t)pix * C) + chq;
            __builtin_nontemporal_store(acc, op);
        }
    }
}

// ---------------- K5: pixel-ordered SH multiply + NCHW transpose write ----------------
__global__ __launch_bounds__(256) void phaseB_kernel(const float* __restrict__ inter,
                                                     const float* __restrict__ sh,
                                                     float* __restrict__ out) {
    __shared__ float shs[256 * 9];
    int base = blockIdx.x * 256;
    const float* shp = sh + (size_t)base * 9;
    for (int i = threadIdx.x; i < 256 * 9; i += 256) shs[i] = shp[i];
    __syncthreads();

    int pix = base + threadIdx.x;
    const float4* ip = reinterpret_cast<const float4*>(inter + (size_t)pix * C);
    float4 a0 = ip[0];
    float4 a1 = ip[1];
    float4 a2 = ip[2];
    float4 a3 = ip[3];
    const float* s = &shs[threadIdx.x * 9];

    a0.w *= s[0];
    a1.x *= s[1]; a1.y *= s[2]; a1.z *= s[3]; a1.w *= s[4];
    a2.x *= s[5]; a2.y *= s[6]; a2.z *= s[7]; a2.w *= s[8];

    int n  = pix >> 18;
    int hw = pix & (HW - 1);
    float* op = out + (size_t)n * C * HW + hw;
    __builtin_nontemporal_store(a0.x, op + 0 * HW);
    __builtin_nontemporal_store(a0.y, op + 1 * HW);
    __builtin_nontemporal_store(a0.z, op + 2 * HW);
    __builtin_nontemporal_store(a0.w, op + 3 * HW);
    __builtin_nontemporal_store(a1.x, op + 4 * HW);
    __builtin_nontemporal_store(a1.y, op + 5 * HW);
    __builtin_nontemporal_store(a1.z, op + 6 * HW);
    __builtin_nontemporal_store(a1.w, op + 7 * HW);
    __builtin_nontemporal_store(a2.x, op + (size_t)8 * HW);
    __builtin_nontemporal_store(a2.y, op + (size_t)9 * HW);
    __builtin_nontemporal_store(a2.z, op + (size_t)10 * HW);
    __builtin_nontemporal_store(a2.w, op + (size_t)11 * HW);
    __builtin_nontemporal_store(a3.x, op + (size_t)12 * HW);
    __builtin_nontemporal_store(a3.y, op + (size_t)13 * HW);
    __builtin_nontemporal_store(a3.z, op + (size_t)14 * HW);
    __builtin_nontemporal_store(a3.w, op + (size_t)15 * HW);
}

// ---------------- Fallback: round-1 monolithic kernel ----------------
__device__ __forceinline__ void tap(const float* __restrict__ t, int S, int iy, int ix,
                                    float w, float acc[C]) {
    if (iy >= 0 && iy < S && ix >= 0 && ix < S) {
        const float4* p = reinterpret_cast<const float4*>(t + ((size_t)iy * S + ix) * C);
        float4 q0 = p[0];
        float4 q1 = p[1];
        float4 q2 = p[2];
        float4 q3 = p[3];
        acc[0]  = fmaf(q0.x, w, acc[0]);
        acc[1]  = fmaf(q0.y, w, acc[1]);
        acc[2]  = fmaf(q0.z, w, acc[2]);
        acc[3]  = fmaf(q0.w, w, acc[3]);
        acc[4]  = fmaf(q1.x, w, acc[4]);
        acc[5]  = fmaf(q1.y, w, acc[5]);
        acc[6]  = fmaf(q1.z, w, acc[6]);
        acc[7]  = fmaf(q1.w, w, acc[7]);
        acc[8]  = fmaf(q2.x, w, acc[8]);
        acc[9]  = fmaf(q2.y, w, acc[9]);
        acc[10] = fmaf(q2.z, w, acc[10]);
        acc[11] = fmaf(q2.w, w, acc[11]);
        acc[12] = fmaf(q3.x, w, acc[12]);
        acc[13] = fmaf(q3.y, w, acc[13]);
        acc[14] = fmaf(q3.z, w, acc[14]);
        acc[15] = fmaf(q3.w, w, acc[15]);
    }
}

__device__ __forceinline__ void sample_level(const float* __restrict__ t, int S,
                                             float u, float v, float acc[C]) {
    float Sf = (float)S;
    float gx = u * 2.0f - 1.0f;
    float gy = -(v * 2.0f - 1.0f);
    float ix = ((gx + 1.0f) * Sf - 1.0f) * 0.5f;
    float iy = ((gy + 1.0f) * Sf - 1.0f) * 0.5f;
    float ix0f = floorf(ix);
    float iy0f = floorf(iy);
    float wx1 = ix - ix0f;
    float wy1 = iy - iy0f;
    float wx0 = 1.0f - wx1;
    float wy0 = 1.0f - wy1;
    int ix0 = (int)ix0f;
    int iy0 = (int)iy0f;
    tap(t, S, iy0,     ix0,     wy0 * wx0, acc);
    tap(t, S, iy0,     ix0 + 1, wy0 * wx1, acc);
    tap(t, S, iy0 + 1, ix0,     wy1 * wx0, acc);
    tap(t, S, iy0 + 1, ix0 + 1, wy1 * wx1, acc);
}

__global__ __launch_bounds__(256) void texmap_kernel(
    const float* __restrict__ uv, const float* __restrict__ sh,
    const float* __restrict__ t0, const float* __restrict__ t1,
    const float* __restrict__ t2, const float* __restrict__ t3,
    float* __restrict__ out) {
    int idx = blockIdx.x * 256 + threadIdx.x;
    if (idx >= NPIX) return;

    float2 uvv = *reinterpret_cast<const float2*>(uv + (size_t)idx * 2);
    float u = uvv.x;
    float v = uvv.y;

    float acc[C];
#pragma unroll
    for (int c = 0; c < C; ++c) acc[c] = 0.0f;

    sample_level(t0, 1024, u, v, acc);
    sample_level(t1, 512,  u, v, acc);
    sample_level(t2, 256,  u, v, acc);
    sample_level(t3, 128,  u, v, acc);

    if (u == 0.0f) {
#pragma unroll
        for (int c = 0; c < C; ++c) acc[c] = 0.0f;
    }

    const float* shp = sh + (size_t)idx * 9;
#pragma unroll
    for (int j = 0; j < 9; ++j) acc[SH_START + j] *= shp[j];

    int n  = idx >> 18;
    int hw = idx & (HW - 1);
    float* op = out + (size_t)n * C * HW + hw;
#pragma unroll
    for (int c = 0; c < C; ++c) {
        __builtin_nontemporal_store(acc[c], op + (size_t)c * HW);
    }
}

extern "C" void kernel_launch(void* const* d_in, const int* in_sizes, int n_in,
                              void* d_out, int out_size, void* d_ws, size_t ws_size,
                              hipStream_t stream) {
    const float* uv = (const float*)d_in[0];
    const float* sh = (const float*)d_in[1];
    const float* t0 = (const float*)d_in[2];
    const float* t1 = (const float*)d_in[3];
    const float* t2 = (const float*)d_in[4];
    const float* t3 = (const float*)d_in[5];
    float* out = (float*)d_out;

    if (ws_size < WS_NEED) {
        texmap_kernel<<<dim3((NPIX + 255) / 256), dim3(256), 0, stream>>>(
            uv, sh, t0, t1, t2, t3, out);
        return;
    }

    char* ws = (char*)d_ws;
    float4* recs    = (float4*)(ws + OFF_RECS);
    float*  inter   = (float*)(ws + OFF_INTER);
    int*    hist    = (int*)(ws + OFF_HIST);
    int*    bstart  = (int*)(ws + OFF_BSTART);

    count_kernel<<<dim3(CNT_BLOCKS), dim3(256), 0, stream>>>(uv, hist);
    scan_kernel<<<dim3(1), dim3(1024), 0, stream>>>(hist, bstart);
    scatter_kernel<<<dim3(CNT_BLOCKS), dim3(256), 0, stream>>>(uv, hist, bstart, recs);
    phaseA_kernel<<<dim3(NBINS), dim3(1024), 0, stream>>>(
        recs, bstart, t0, t1, t2, t3, inter);
    phaseB_kernel<<<dim3(NPIX / 256), dim3(256), 0, stream>>>(inter, sh, out);
}